// Round 9
// baseline (13002.643 us; speedup 1.0000x reference)
//
#include <hip/hip_runtime.h>
#include <cstddef>
#include <cstdint>

constexpr int B  = 48;
constexpr int L  = 192;
constexpr int T  = 193;    // L + 1
constexpr int KD = 1024;   // I == H
constexpr int G3 = 3072;   // 3*H
constexpr int V  = 8192;
constexpr int M  = T * B;  // 9264
constexpr int SB = 128;    // scan blocks per layer: 8 h-channels each

typedef float f32x4 __attribute__((ext_vector_type(4)));
typedef short s16x8 __attribute__((ext_vector_type(8)));
typedef unsigned short u16x8 __attribute__((ext_vector_type(8)));

__device__ inline unsigned short f2bf(float f) {
  unsigned u = __builtin_bit_cast(unsigned, f);
  u += 0x7fffu + ((u >> 16) & 1u);   // round-to-nearest-even
  return (unsigned short)(u >> 16);
}
__device__ inline float bf2f(unsigned short h) {
  return __builtin_bit_cast(float, (unsigned)h << 16);
}

// ---------------------------------------------------------------------------
__global__ __launch_bounds__(256)
void init_h0(const float* __restrict__ et, const int* __restrict__ ids,
             float* __restrict__ h0f, unsigned short* __restrict__ h0hi,
             unsigned short* __restrict__ h0lo) {
  int b = blockIdx.x;
  int id = ids[b];
  float4 v = ((const float4*)(et + (size_t)id * KD))[threadIdx.x];
  ((float4*)(h0f + (size_t)b * KD))[threadIdx.x] = v;
  int base = b * KD + threadIdx.x * 4;
  float vv[4] = {v.x, v.y, v.z, v.w};
#pragma unroll
  for (int j = 0; j < 4; ++j) {
    unsigned short hi = f2bf(vv[j]);
    h0hi[base + j] = hi;
    h0lo[base + j] = f2bf(vv[j] - bf2f(hi));
  }
}

// fp32 -> bf16 (raw bits), 8 elems/thread
__global__ __launch_bounds__(256)
void cvt_bf16(const float* __restrict__ in, unsigned short* __restrict__ out,
              long long n) {
  long long i = ((long long)blockIdx.x * 256 + threadIdx.x) * 8;
  if (i + 8 > n) return;
  float4 v0 = *(const float4*)(in + i);
  float4 v1 = *(const float4*)(in + i + 4);
  u16x8 o;
  o[0] = f2bf(v0.x); o[1] = f2bf(v0.y); o[2] = f2bf(v0.z); o[3] = f2bf(v0.w);
  o[4] = f2bf(v1.x); o[5] = f2bf(v1.y); o[6] = f2bf(v1.z); o[7] = f2bf(v1.w);
  *(u16x8*)(out + i) = o;
}

// ---------------------------------------------------------------------------
// Repack [3*KD, KD] fp32 weights -> per-block split-bf16 [SB][32][KD] (hi,lo).
__global__ __launch_bounds__(256)
void repack_whh(const float* __restrict__ w_hh, unsigned short* __restrict__ hi,
                unsigned short* __restrict__ lo) {
  long long idx = ((long long)blockIdx.x * 256 + threadIdx.x) * 8;
  if (idx >= (long long)SB * 32 * KD) return;
  int k  = (int)(idx & (KD - 1));
  int rr = (int)(idx >> 10);
  int r = rr & 31, bid = rr >> 5;
  u16x8 h8 = (u16x8)0, l8 = (u16x8)0;
  if (r < 24) {
    int g = r >> 3, c = bid * 8 + (r & 7);
    const float* src = w_hh + ((size_t)(g * KD + c)) * KD + k;
    float4 v0 = *(const float4*)src, v1 = *(const float4*)(src + 4);
    float vv[8] = {v0.x, v0.y, v0.z, v0.w, v1.x, v1.y, v1.z, v1.w};
#pragma unroll
    for (int j = 0; j < 8; ++j) {
      unsigned short h = f2bf(vv[j]);
      h8[j] = h;
      l8[j] = f2bf(vv[j] - bf2f(h));
    }
  }
  *(u16x8*)(hi + idx) = h8;
  *(u16x8*)(lo + idx) = l8;
}

// Same packing, single bf16 (for w_ih1 used by the on-the-fly x-projection).
__global__ __launch_bounds__(256)
void repack_w_single(const float* __restrict__ w, unsigned short* __restrict__ pk) {
  long long idx = ((long long)blockIdx.x * 256 + threadIdx.x) * 8;
  if (idx >= (long long)SB * 32 * KD) return;
  int k  = (int)(idx & (KD - 1));
  int rr = (int)(idx >> 10);
  int r = rr & 31, bid = rr >> 5;
  u16x8 h8 = (u16x8)0;
  if (r < 24) {
    int g = r >> 3, c = bid * 8 + (r & 7);
    const float* src = w + ((size_t)(g * KD + c)) * KD + k;
    float4 v0 = *(const float4*)src, v1 = *(const float4*)(src + 4);
    float vv[8] = {v0.x, v0.y, v0.z, v0.w, v1.x, v1.y, v1.z, v1.w};
#pragma unroll
    for (int j = 0; j < 8; ++j) h8[j] = f2bf(vv[j]);
  }
  *(u16x8*)(pk + idx) = h8;
}

// ---------------------------------------------------------------------------
// bf16 MFMA GEMM (validated R2/R7): C[m,n] = sum_k A[m,k]*W[n,k] + bias[n].
template<int GATHER, int OUTMODE>
__global__ __launch_bounds__(256)
void gemm_bf16(const unsigned short* __restrict__ A,
               const unsigned short* __restrict__ W,
               const float* __restrict__ bias, float* __restrict__ C, int Ndim,
               const int* __restrict__ seq,
               const unsigned short* __restrict__ start_bf,
               const unsigned short* __restrict__ table_bf) {
  __shared__ __align__(16) unsigned short a_s[128 * 32];
  __shared__ __align__(16) unsigned short b_s[128 * 32];
  const int tid  = threadIdx.x;
  const int lane = tid & 63;
  const int wave = tid >> 6;
  const int m0 = blockIdx.x * 128;
  const int n0 = blockIdx.y * 128;
  const int wr = wave >> 1, wc = wave & 1;

  f32x4 acc[4][4];
#pragma unroll
  for (int i = 0; i < 4; ++i)
#pragma unroll
    for (int j = 0; j < 4; ++j) acc[i][j] = (f32x4){0.f, 0.f, 0.f, 0.f};

  const int lrow = lane & 15;
  const int lkhi = lane >> 4;

  for (int kt = 0; kt < KD; kt += 32) {
    __syncthreads();
#pragma unroll
    for (int j = 0; j < 2; ++j) {
      int flat = tid * 16 + j * 4096;
      int row = flat >> 6;
      int cc = (flat >> 4) & 3;
      const unsigned short* src;
      if (GATHER) {
        int m = m0 + row; if (m >= M) m = 0;
        int t = m / B, b = m - t * B;
        const unsigned short* rowsrc =
            (t == 0) ? start_bf : (table_bf + (size_t)seq[b * L + t - 1] * KD);
        src = rowsrc + kt + cc * 8;
      } else {
        int m = m0 + row; if (m >= M) m = 0;
        src = A + (size_t)m * KD + kt + cc * 8;
      }
      *(int4*)((char*)a_s + flat) = *(const int4*)src;
    }
#pragma unroll
    for (int j = 0; j < 2; ++j) {
      int flat = tid * 16 + j * 4096;
      int row = flat >> 6;
      int cc = (flat >> 4) & 3;
      const unsigned short* src = W + (size_t)(n0 + row) * KD + kt + cc * 8;
      *(int4*)((char*)b_s + flat) = *(const int4*)src;
    }
    __syncthreads();

    s16x8 af[4], wf[4];
#pragma unroll
    for (int i = 0; i < 4; ++i) {
      int arow = wr * 64 + i * 16 + lrow;
      af[i] = *(const s16x8*)((const char*)a_s + arow * 64 + lkhi * 16);
      int brow = wc * 64 + i * 16 + lrow;
      wf[i] = *(const s16x8*)((const char*)b_s + brow * 64 + lkhi * 16);
    }
#pragma unroll
    for (int i = 0; i < 4; ++i)
#pragma unroll
      for (int j = 0; j < 4; ++j)
        acc[i][j] = __builtin_amdgcn_mfma_f32_16x16x32_bf16(af[i], wf[j],
                                                            acc[i][j], 0, 0, 0);
  }

#pragma unroll
  for (int i = 0; i < 4; ++i) {
#pragma unroll
    for (int r = 0; r < 4; ++r) {
      int m = m0 + wr * 64 + i * 16 + (lane >> 4) * 4 + r;
      if (m >= M) continue;
      size_t rowoff;
      if (OUTMODE == 0) {
        rowoff = (size_t)m * (size_t)Ndim;
      } else {
        int t = m / B, b = m - t * B;
        rowoff = ((size_t)b * T + t) * (size_t)Ndim;
      }
#pragma unroll
      for (int j = 0; j < 4; ++j) {
        int n = n0 + wc * 64 + j * 16 + (lane & 15);
        C[rowoff + n] = acc[i][j][r] + bias[n];
      }
    }
  }
}

// ---------------------------------------------------------------------------
// Core of one GRU step for one block's 8 channels (validated R7).
template<int HASX>
__device__ __forceinline__ void gru_core(
    int c0, int tid,
    const float* __restrict__ xp_t, const unsigned short* __restrict__ Xhi,
    const unsigned short* __restrict__ wih_pk, const float* __restrict__ b_ih,
    const unsigned short* __restrict__ wb_hi, const unsigned short* __restrict__ wb_lo,
    const float* __restrict__ b_hh,
    const unsigned short* __restrict__ Shi, const unsigned short* __restrict__ Slo,
    const float* __restrict__ h_old, float* __restrict__ h_new,
    unsigned short* __restrict__ y_hi, unsigned short* __restrict__ y_lo,
    float (*cp_h)[48 * 33], float (*cp_x)[48 * 33]) {
  const int lane = tid & 63, wave = tid >> 6;
  const int lrow = lane & 15, lkhi = lane >> 4;

  f32x4 acc_h[3][2], acc_x[3][2];
#pragma unroll
  for (int i = 0; i < 3; ++i)
#pragma unroll
    for (int j = 0; j < 2; ++j) {
      acc_h[i][j] = (f32x4){0.f, 0.f, 0.f, 0.f};
      acc_x[i][j] = (f32x4){0.f, 0.f, 0.f, 0.f};
    }

#pragma unroll
  for (int ks = 0; ks < 8; ++ks) {
    int k0 = wave * 256 + ks * 32 + lkhi * 8;
    s16x8 ah[3], al[3], xh[3];
#pragma unroll
    for (int mt = 0; mt < 3; ++mt) {
      int b = mt * 16 + lrow;
      ah[mt] = *(const s16x8*)(Shi + (size_t)b * KD + k0);
      al[mt] = *(const s16x8*)(Slo + (size_t)b * KD + k0);
      if (HASX) xh[mt] = *(const s16x8*)(Xhi + (size_t)b * KD + k0);
    }
    s16x8 bh[2], bl[2], wx[2];
#pragma unroll
    for (int nt = 0; nt < 2; ++nt) {
      int r = nt * 16 + lrow;
      bh[nt] = *(const s16x8*)(wb_hi + (size_t)r * KD + k0);
      bl[nt] = *(const s16x8*)(wb_lo + (size_t)r * KD + k0);
      if (HASX) wx[nt] = *(const s16x8*)(wih_pk + (size_t)r * KD + k0);
    }
#pragma unroll
    for (int mt = 0; mt < 3; ++mt)
#pragma unroll
      for (int nt = 0; nt < 2; ++nt) {
        acc_h[mt][nt] = __builtin_amdgcn_mfma_f32_16x16x32_bf16(ah[mt], bh[nt], acc_h[mt][nt], 0, 0, 0);
        acc_h[mt][nt] = __builtin_amdgcn_mfma_f32_16x16x32_bf16(al[mt], bh[nt], acc_h[mt][nt], 0, 0, 0);
        acc_h[mt][nt] = __builtin_amdgcn_mfma_f32_16x16x32_bf16(ah[mt], bl[nt], acc_h[mt][nt], 0, 0, 0);
        if (HASX)
          acc_x[mt][nt] = __builtin_amdgcn_mfma_f32_16x16x32_bf16(xh[mt], wx[nt], acc_x[mt][nt], 0, 0, 0);
      }
  }

#pragma unroll
  for (int mt = 0; mt < 3; ++mt)
#pragma unroll
    for (int nt = 0; nt < 2; ++nt)
#pragma unroll
      for (int r = 0; r < 4; ++r) {
        int row = mt * 16 + (lane >> 4) * 4 + r;
        int col = nt * 16 + (lane & 15);
        cp_h[wave][row * 33 + col] = acc_h[mt][nt][r];
        if (HASX) cp_x[wave][row * 33 + col] = acc_x[mt][nt][r];
      }
  __syncthreads();

  for (int p = tid; p < 384; p += 256) {
    int b = p >> 3, c = p & 7;
    float pr = 0.f, pz = 0.f, pn = 0.f;
    float xr, xz, xn;
#pragma unroll
    for (int w = 0; w < 4; ++w) {
      pr += cp_h[w][b * 33 + c];
      pz += cp_h[w][b * 33 + 8 + c];
      pn += cp_h[w][b * 33 + 16 + c];
    }
    int gc = c0 + c;
    if (HASX) {
      float qr = 0.f, qz = 0.f, qn = 0.f;
#pragma unroll
      for (int w = 0; w < 4; ++w) {
        qr += cp_x[w][b * 33 + c];
        qz += cp_x[w][b * 33 + 8 + c];
        qn += cp_x[w][b * 33 + 16 + c];
      }
      xr = qr + b_ih[gc];
      xz = qz + b_ih[KD + gc];
      xn = qn + b_ih[2 * KD + gc];
    } else {
      const float* xrow = xp_t + (size_t)b * G3;
      xr = xrow[gc]; xz = xrow[KD + gc]; xn = xrow[2 * KD + gc];
    }
    float hr = pr + b_hh[gc];
    float hz = pz + b_hh[KD + gc];
    float hn = pn + b_hh[2 * KD + gc];
    float r_ = 1.f / (1.f + expf(-(xr + hr)));
    float z_ = 1.f / (1.f + expf(-(xz + hz)));
    float n_ = tanhf(xn + r_ * hn);
    float hold = h_old[(size_t)b * KD + gc];
    float hnew = (1.f - z_) * n_ + z_ * hold;
    h_new[(size_t)b * KD + gc] = hnew;
    unsigned short hi = f2bf(hnew);
    y_hi[(size_t)b * KD + gc] = hi;
    y_lo[(size_t)b * KD + gc] = f2bf(hnew - bf2f(hi));
  }
}

// ---------------------------------------------------------------------------
// Manual device-wide barrier: generation counter in global memory.
// bar[0] = arrive count, bar[1] = generation. Must be zeroed before launch.
__device__ __forceinline__ void grid_barrier(unsigned* bar) {
  __syncthreads();                       // all waves' stores drained (vmcnt) + block sync
  if (threadIdx.x == 0) {
    __threadfence();                     // release: write back this XCD's L2
    unsigned g = __atomic_load_n(bar + 1, __ATOMIC_RELAXED);
    unsigned arrived = __atomic_add_fetch(bar, 1u, __ATOMIC_ACQ_REL);
    if (arrived == 2u * SB) {
      __atomic_store_n(bar, 0u, __ATOMIC_RELAXED);
      __atomic_store_n(bar + 1, g + 1u, __ATOMIC_RELEASE);
    } else {
      int spins = 0;
      while (__atomic_load_n(bar + 1, __ATOMIC_ACQUIRE) == g) {
        if (++spins > (1 << 18)) break;  // failsafe: wrong results, never a hang
        __builtin_amdgcn_s_sleep(2);
      }
    }
    __threadfence();                     // acquire: invalidate L1/L2 before next reads
  }
  __syncthreads();
}

// ---------------------------------------------------------------------------
// Persistent pipelined two-layer scan, plain launch + manual barrier.
// Iteration t: blocks [0,SB) do layer0 step t; [SB,2SB) do layer1 step t-1.
struct ScanArgs {
  const float* xp0;
  const unsigned short* wpk0_hi; const unsigned short* wpk0_lo; const float* b_hh0;
  const unsigned short* wpk1_hi; const unsigned short* wpk1_lo;
  const unsigned short* wih1pk;  const float* b_ih1; const float* b_hh1;
  const unsigned short* h0hi;    const unsigned short* h0lo; const float* h0f;
  unsigned short* ys0_bf; unsigned short* lo0a; unsigned short* lo0b; float* h0f32;
  unsigned short* ys1_bf; unsigned short* lo1a; unsigned short* lo1b; float* h1f32;
  unsigned* bar;
};

__global__ __launch_bounds__(256, 1)
void gru_scan_persist(ScanArgs a) {
  __shared__ float cp_h[4][48 * 33];
  __shared__ float cp_x[4][48 * 33];
  const int tid = threadIdx.x;
  const bool is1 = blockIdx.x >= SB;
  const int bid = is1 ? (int)blockIdx.x - SB : (int)blockIdx.x;
  const int c0 = bid * 8;

  for (int t = 0; t <= T; ++t) {
    if (!is1) {
      if (t < T) {
        const unsigned short* Shi = (t == 0) ? a.h0hi : a.ys0_bf + (size_t)(t - 1) * B * KD;
        const unsigned short* Slo = (t == 0) ? a.h0lo : (((t - 1) & 1) ? a.lo0b : a.lo0a);
        const float* hold = (t == 0) ? a.h0f : a.h0f32;
        gru_core<0>(c0, tid, a.xp0 + (size_t)t * B * G3, nullptr, nullptr, nullptr,
                    a.wpk0_hi + (size_t)bid * 32 * KD, a.wpk0_lo + (size_t)bid * 32 * KD,
                    a.b_hh0, Shi, Slo, hold, a.h0f32,
                    a.ys0_bf + (size_t)t * B * KD, (t & 1) ? a.lo0b : a.lo0a,
                    cp_h, cp_x);
      }
    } else {
      int s = t - 1;
      if (s >= 0) {
        const unsigned short* Shi = (s == 0) ? a.h0hi : a.ys1_bf + (size_t)(s - 1) * B * KD;
        const unsigned short* Slo = (s == 0) ? a.h0lo : (((s - 1) & 1) ? a.lo1b : a.lo1a);
        const float* hold = (s == 0) ? a.h0f : a.h1f32;
        gru_core<1>(c0, tid, nullptr, a.ys0_bf + (size_t)s * B * KD,
                    a.wih1pk + (size_t)bid * 32 * KD, a.b_ih1,
                    a.wpk1_hi + (size_t)bid * 32 * KD, a.wpk1_lo + (size_t)bid * 32 * KD,
                    a.b_hh1, Shi, Slo, hold, a.h1f32,
                    a.ys1_bf + (size_t)s * B * KD, (s & 1) ? a.lo1b : a.lo1a,
                    cp_h, cp_x);
      }
    }
    grid_barrier(a.bar);
  }
}

// ---------------------------------------------------------------------------
__global__ __launch_bounds__(256)
void softmax_mask(float* __restrict__ out, const int* __restrict__ seq) {
  const int t = blockIdx.x, b = blockIdx.y;
  float* row = out + ((size_t)b * T + t) * V;
  __shared__ unsigned bits[V / 32];
  __shared__ float red[4];
  const int tid = threadIdx.x;
  const bool masked = (t < L - 1);
  if (masked) {
    bits[tid] = 0u;
    __syncthreads();
    int rem = L - t;
    if (tid < rem) {
      int id = seq[b * L + t + tid];
      atomicOr(&bits[id >> 5], 1u << (id & 31));
    }
  }
  __syncthreads();

  float4 x[8];
  float mx = -3.0e38f;
#pragma unroll
  for (int j = 0; j < 8; ++j) {
    float4 v = ((const float4*)row)[j * 256 + tid];
    if (masked) {
      int vb = (j * 256 + tid) * 4;
      unsigned wrd = bits[vb >> 5];
      int sh = vb & 31;
      if (!((wrd >> (sh + 0)) & 1u)) v.x = -1.0e30f;
      if (!((wrd >> (sh + 1)) & 1u)) v.y = -1.0e30f;
      if (!((wrd >> (sh + 2)) & 1u)) v.z = -1.0e30f;
      if (!((wrd >> (sh + 3)) & 1u)) v.w = -1.0e30f;
    }
    x[j] = v;
    mx = fmaxf(mx, fmaxf(fmaxf(v.x, v.y), fmaxf(v.z, v.w)));
  }
#pragma unroll
  for (int off = 32; off > 0; off >>= 1) mx = fmaxf(mx, __shfl_xor(mx, off));
  int wv = tid >> 6;
  if ((tid & 63) == 0) red[wv] = mx;
  __syncthreads();
  mx = fmaxf(fmaxf(red[0], red[1]), fmaxf(red[2], red[3]));

  float s = 0.f;
#pragma unroll
  for (int j = 0; j < 8; ++j) {
    x[j].x = expf(x[j].x - mx); x[j].y = expf(x[j].y - mx);
    x[j].z = expf(x[j].z - mx); x[j].w = expf(x[j].w - mx);
    s += x[j].x + x[j].y + x[j].z + x[j].w;
  }
#pragma unroll
  for (int off = 32; off > 0; off >>= 1) s += __shfl_xor(s, off);
  __syncthreads();
  if ((tid & 63) == 0) red[wv] = s;
  __syncthreads();
  s = red[0] + red[1] + red[2] + red[3];
  float inv = 1.f / s;
#pragma unroll
  for (int j = 0; j < 8; ++j) {
    float4 v = make_float4(x[j].x * inv, x[j].y * inv, x[j].z * inv, x[j].w * inv);
    ((float4*)row)[j * 256 + tid] = v;
  }
}

// ---------------------------------------------------------------------------
extern "C" void kernel_launch(void* const* d_in, const int* in_sizes, int n_in,
                              void* d_out, int out_size, void* d_ws, size_t ws_size,
                              hipStream_t stream) {
  const float* event_table = (const float*)d_in[0];
  const float* user_table  = (const float*)d_in[1];
  const float* startv      = (const float*)d_in[2];
  const float* w_ih0 = (const float*)d_in[3];
  const float* w_hh0 = (const float*)d_in[4];
  const float* b_ih0 = (const float*)d_in[5];
  const float* b_hh0 = (const float*)d_in[6];
  const float* w_ih1 = (const float*)d_in[7];
  const float* w_hh1 = (const float*)d_in[8];
  const float* b_ih1 = (const float*)d_in[9];
  const float* b_hh1 = (const float*)d_in[10];
  const float* lin_w = (const float*)d_in[11];
  const float* lin_b = (const float*)d_in[12];
  const int*   ids   = (const int*)d_in[13];
  const int*   seq   = (const int*)d_in[14];
  float* out = (float*)d_out;

  // workspace layout (~235 MB)
  float* xp0  = (float*)d_ws;                           // M*G3 f32
  float* h0f  = xp0 + (size_t)M * G3;                   // B*KD
  float* h0f32 = h0f + (size_t)B * KD;                  // B*KD (layer0 state)
  float* h1f32 = h0f32 + (size_t)B * KD;                // B*KD (layer1 state)
  unsigned short* ut_bf    = (unsigned short*)(h1f32 + (size_t)B * KD);
  unsigned short* start_bf = ut_bf    + (size_t)V * KD;
  unsigned short* wih0_bf  = start_bf + KD;
  unsigned short* linw_bf  = wih0_bf  + (size_t)G3 * KD;
  unsigned short* ys0_bf   = linw_bf  + (size_t)V * KD;
  unsigned short* ys1_bf   = ys0_bf   + (size_t)M * KD;
  unsigned short* h0hi     = ys1_bf   + (size_t)M * KD;
  unsigned short* h0lo     = h0hi + (size_t)B * KD;
  unsigned short* lo0a     = h0lo + (size_t)B * KD;
  unsigned short* lo0b     = lo0a + (size_t)B * KD;
  unsigned short* lo1a     = lo0b + (size_t)B * KD;
  unsigned short* lo1b     = lo1a + (size_t)B * KD;
  unsigned short* wpk0_hi  = lo1b + (size_t)B * KD;
  unsigned short* wpk0_lo  = wpk0_hi + (size_t)SB * 32 * KD;
  unsigned short* wpk1_hi  = wpk0_lo + (size_t)SB * 32 * KD;
  unsigned short* wpk1_lo  = wpk1_hi + (size_t)SB * 32 * KD;
  unsigned short* wih1pk   = wpk1_lo + (size_t)SB * 32 * KD;
  unsigned* bar            = (unsigned*)(wih1pk + (size_t)SB * 32 * KD);

  init_h0<<<dim3(B), 256, 0, stream>>>(event_table, ids, h0f, h0hi, h0lo);

  auto cvt = [&](const float* src, unsigned short* dst, long long n) {
    int blocks = (int)((n + 2047) / 2048);
    cvt_bf16<<<dim3(blocks), 256, 0, stream>>>(src, dst, n);
  };
  cvt(user_table, ut_bf,    (long long)V * KD);
  cvt(startv,     start_bf, KD);
  cvt(w_ih0,      wih0_bf,  (long long)G3 * KD);
  cvt(lin_w,      linw_bf,  (long long)V * KD);

  repack_whh<<<dim3(SB * 32 * KD / 2048), 256, 0, stream>>>(w_hh0, wpk0_hi, wpk0_lo);
  repack_whh<<<dim3(SB * 32 * KD / 2048), 256, 0, stream>>>(w_hh1, wpk1_hi, wpk1_lo);
  repack_w_single<<<dim3(SB * 32 * KD / 2048), 256, 0, stream>>>(w_ih1, wih1pk);

  // layer 0 input projection (gather from bf16 tables)
  gemm_bf16<1, 0><<<dim3((M + 127) / 128, G3 / 128), 256, 0, stream>>>(
      nullptr, wih0_bf, b_ih0, xp0, G3, seq, start_bf, ut_bf);

  // zero the barrier state (graph-capturable), then persistent scan
  hipMemsetAsync(bar, 0, 2 * sizeof(unsigned), stream);
  {
    ScanArgs sa;
    sa.xp0 = xp0;
    sa.wpk0_hi = wpk0_hi; sa.wpk0_lo = wpk0_lo; sa.b_hh0 = b_hh0;
    sa.wpk1_hi = wpk1_hi; sa.wpk1_lo = wpk1_lo;
    sa.wih1pk = wih1pk;   sa.b_ih1 = b_ih1;     sa.b_hh1 = b_hh1;
    sa.h0hi = h0hi; sa.h0lo = h0lo; sa.h0f = h0f;
    sa.ys0_bf = ys0_bf; sa.lo0a = lo0a; sa.lo0b = lo0b; sa.h0f32 = h0f32;
    sa.ys1_bf = ys1_bf; sa.lo1a = lo1a; sa.lo1b = lo1b; sa.h1f32 = h1f32;
    sa.bar = bar;
    gru_scan_persist<<<dim3(2 * SB), dim3(256), 0, stream>>>(sa);
  }

  // logits into d_out at [b][t][v]
  gemm_bf16<0, 1><<<dim3((M + 127) / 128, V / 128), 256, 0, stream>>>(
      ys1_bf, linw_bf, lin_b, out, V, nullptr, nullptr, nullptr);

  // masked softmax in place
  softmax_mask<<<dim3(T, B), 256, 0, stream>>>(out, seq);
}